// Round 12
// baseline (375.905 us; speedup 1.0000x reference)
//
#include <hip/hip_runtime.h>
#include <hip/hip_bf16.h>
#include <stdint.h>

typedef float  f32x4  __attribute__((ext_vector_type(4)));
typedef short  bf16x8 __attribute__((ext_vector_type(8)));

__device__ __forceinline__ unsigned short f2bf(float f) {
  union { __hip_bfloat16 b; unsigned short u; } cv;
  cv.b = __float2bfloat16(f);
  return cv.u;
}

// ---- DPP 16-lane rotate-reductions (row_ror:n = 0x120|n), full-rate VALU ----
template <int CTRL>
__device__ __forceinline__ float dpp_mv(float x) {
  int v = __builtin_bit_cast(int, x);
  v = __builtin_amdgcn_update_dpp(v, v, CTRL, 0xF, 0xF, false);
  return __builtin_bit_cast(float, v);
}
__device__ __forceinline__ float rowmax16(float x) {
  x = fmaxf(x, dpp_mv<0x121>(x));
  x = fmaxf(x, dpp_mv<0x122>(x));
  x = fmaxf(x, dpp_mv<0x124>(x));
  x = fmaxf(x, dpp_mv<0x128>(x));
  return x;
}
__device__ __forceinline__ float rowsum16(float x) {
  x += dpp_mv<0x121>(x);
  x += dpp_mv<0x122>(x);
  x += dpp_mv<0x124>(x);
  x += dpp_mv<0x128>(x);
  return x;
}

// =================== elementwise converts ===================
// 8 floats/thread: 2x float4 load -> one 16B bf16x8 store (grid 4096).
__global__ __launch_bounds__(256) void k_cvt_bf16(const float* __restrict__ in,
                                                  __hip_bfloat16* __restrict__ out) {
  size_t i = (size_t)blockIdx.x * 256 + threadIdx.x;
  float4 a = *(const float4*)(in + i * 8);
  float4 b = *(const float4*)(in + i * 8 + 4);
  bf16x8 o;
  o[0] = (short)f2bf(a.x); o[1] = (short)f2bf(a.y);
  o[2] = (short)f2bf(a.z); o[3] = (short)f2bf(a.w);
  o[4] = (short)f2bf(b.x); o[5] = (short)f2bf(b.y);
  o[6] = (short)f2bf(b.z); o[7] = (short)f2bf(b.w);
  *(bf16x8*)(out + i * 8) = o;
}

// in [K][N] fp32 -> out [N][K] bf16 (32x32 LDS tile transpose)
__global__ __launch_bounds__(256) void k_transpose_bf16(const float* __restrict__ in,
                                                        __hip_bfloat16* __restrict__ out,
                                                        int K, int N) {
  __shared__ float tile[32][33];
  int t = threadIdx.x;
  int k0 = blockIdx.y * 32, n0 = blockIdx.x * 32;
  {
    int kl = t >> 3, nl = (t & 7) * 4;
    float4 v = *(const float4*)(in + (size_t)(k0 + kl) * N + n0 + nl);
    tile[kl][nl] = v.x; tile[kl][nl + 1] = v.y; tile[kl][nl + 2] = v.z; tile[kl][nl + 3] = v.w;
  }
  __syncthreads();
  {
    int nl = t >> 3, kl = (t & 7) * 4;
    union { short4 s; unsigned short u[4]; } o;
    #pragma unroll
    for (int i = 0; i < 4; ++i) o.u[i] = f2bf(tile[kl + i][nl]);
    *(short4*)(out + (size_t)(n0 + nl) * K + k0 + kl) = o.s;
  }
}

// =================== GEMM (A row-major, Bt = B^T row-major, both bf16) ===================
__device__ __forceinline__ void stage128x32(const __hip_bfloat16* gsrc_row0, int ld_elem,
                                            char* lds_tile, int t) {
  int w = t >> 6, lam = t & 63;
  #pragma unroll
  for (int i = 0; i < 2; ++i) {
    int idx = w * 1024 + i * 4096 + lam * 16;
    int row = idx >> 6;
    int cph = (idx >> 4) & 3;
    int csrc = cph ^ ((row >> 1) & 3);
    const char* src = (const char*)(gsrc_row0 + (size_t)row * ld_elem) + csrc * 16;
    __builtin_amdgcn_global_load_lds(
        (const __attribute__((address_space(1))) uint32_t*)src,
        (__attribute__((address_space(3))) uint32_t*)(lds_tile + w * 1024 + i * 4096),
        16, 0, 0);
  }
}

__device__ __forceinline__ bf16x8 frag64(const char* tile, int row, int chunk) {
  int c = chunk ^ ((row >> 1) & 3);
  return *(const bf16x8*)(tile + row * 64 + c * 16);
}

// C = swish(A @ Bt^T + bias) -> bf16
__global__ __launch_bounds__(256) void k_gemm_fc(const __hip_bfloat16* __restrict__ A,
                                                 const __hip_bfloat16* __restrict__ Bt,
                                                 const float* __restrict__ bias,
                                                 __hip_bfloat16* __restrict__ C,
                                                 int M, int N, int K) {
  __shared__ char lds[16384];
  char* As = lds; char* Bs = lds + 8192;
  const int t = threadIdx.x, l = t & 63, w = t >> 6;
  const int bm0 = blockIdx.y * 128, bn0 = blockIdx.x * 128;
  const int wm = (w >> 1) * 64, wn = (w & 1) * 64;
  f32x4 acc[4][4] = {};
  for (int kt = 0; kt < K; kt += 32) {
    stage128x32(A + (size_t)bm0 * K + kt, K, As, t);
    stage128x32(Bt + (size_t)bn0 * K + kt, K, Bs, t);
    __syncthreads();
    bf16x8 af[4], bfr[4];
    #pragma unroll
    for (int mi = 0; mi < 4; ++mi) af[mi] = frag64(As, wm + mi * 16 + (l & 15), l >> 4);
    #pragma unroll
    for (int ni = 0; ni < 4; ++ni) bfr[ni] = frag64(Bs, wn + ni * 16 + (l & 15), l >> 4);
    #pragma unroll
    for (int mi = 0; mi < 4; ++mi)
      #pragma unroll
      for (int ni = 0; ni < 4; ++ni)
        acc[mi][ni] = __builtin_amdgcn_mfma_f32_16x16x32_bf16(af[mi], bfr[ni], acc[mi][ni], 0, 0, 0);
    __syncthreads();
  }
  #pragma unroll
  for (int mi = 0; mi < 4; ++mi)
    #pragma unroll
    for (int ni = 0; ni < 4; ++ni)
      #pragma unroll
      for (int r = 0; r < 4; ++r) {
        int row = bm0 + wm + mi * 16 + (l >> 4) * 4 + r;
        int col = bn0 + wn + ni * 16 + (l & 15);
        float v = acc[mi][ni][r] + bias[col];
        v = v / (1.0f + __expf(-v));
        *(unsigned short*)((char*)C + ((size_t)row * N + col) * 2) = f2bf(v);
      }
}

// C = swish(A @ Bt^T + bias) + X  -> fp32
__global__ __launch_bounds__(256) void k_gemm_out(const __hip_bfloat16* __restrict__ A,
                                                  const __hip_bfloat16* __restrict__ Bt,
                                                  const float* __restrict__ bias,
                                                  const float* __restrict__ X,
                                                  float* __restrict__ C,
                                                  int M, int N, int K) {
  __shared__ char lds[16384];
  char* As = lds; char* Bs = lds + 8192;
  const int t = threadIdx.x, l = t & 63, w = t >> 6;
  const int bm0 = blockIdx.y * 128, bn0 = blockIdx.x * 128;
  const int wm = (w >> 1) * 64, wn = (w & 1) * 64;
  f32x4 acc[4][4] = {};
  for (int kt = 0; kt < K; kt += 32) {
    stage128x32(A + (size_t)bm0 * K + kt, K, As, t);
    stage128x32(Bt + (size_t)bn0 * K + kt, K, Bs, t);
    __syncthreads();
    bf16x8 af[4], bfr[4];
    #pragma unroll
    for (int mi = 0; mi < 4; ++mi) af[mi] = frag64(As, wm + mi * 16 + (l & 15), l >> 4);
    #pragma unroll
    for (int ni = 0; ni < 4; ++ni) bfr[ni] = frag64(Bs, wn + ni * 16 + (l & 15), l >> 4);
    #pragma unroll
    for (int mi = 0; mi < 4; ++mi)
      #pragma unroll
      for (int ni = 0; ni < 4; ++ni)
        acc[mi][ni] = __builtin_amdgcn_mfma_f32_16x16x32_bf16(af[mi], bfr[ni], acc[mi][ni], 0, 0, 0);
    __syncthreads();
  }
  #pragma unroll
  for (int mi = 0; mi < 4; ++mi)
    #pragma unroll
    for (int ni = 0; ni < 4; ++ni)
      #pragma unroll
      for (int r = 0; r < 4; ++r) {
        int row = bm0 + wm + mi * 16 + (l >> 4) * 4 + r;
        int col = bn0 + wn + ni * 16 + (l & 15);
        float v = acc[mi][ni][r] + bias[col];
        v = v / (1.0f + __expf(-v));
        v += X[(size_t)row * N + col];
        C[(size_t)row * N + col] = v;
      }
}

// =================== flash attention v3.11 (R8 body, 128-row staging groups) ===================
// The 64-row inner body (QK^T -> softmax -> PV) is BYTE-IDENTICAL to proven
// R8/R11, executed twice per group at +sb*8192 LDS offsets.  Barrier topology
// is exactly R8's two-barrier scheme at HALF frequency: 16 groups x 2 barriers
// instead of 32 tiles x 2 — halves the vmcnt(0)-drain stalls that dominate
// (5.8k cyc/iter elapsed vs ~900 cyc issue-work).  K staging extends the
// proven pattern (i<2 -> i<4; rows 64..127 land at +8KB, row-mod-8 alignment
// preserved so the XOR swizzle is unchanged).  V: vreg doubled (+8 VGPR),
// both sub-tiles written between the barriers.  P wave-private, reused (no
// barrier needed — proven in R8).  LDS 65536 (K 2x16K dbuf, V 16K, P 16K);
// 2 blocks/CU by LDS = existing register limit, co-residency unchanged.
// POISONED (empirically fail on HW; no disasm here — do not retry):
//   * m-init-0 + C-init fold of -m into QK^T MFMA      (R4 6.0, R5 1.55)
//   * l via ones-column MFMA accumulation              (R7 6.52)
//   * single-barrier V-dbuf merged with this softmax   (R10 0.203)
//   * __launch_bounds__ min-waves hint                 (R2 spill)
// Also: 16-row warps regressed (R9); OccupancyPercent reads ~0.5x theoretical.
__global__ __launch_bounds__(256) void k_attn(const __hip_bfloat16* __restrict__ qkv,
                                              __hip_bfloat16* __restrict__ nv) {
  __shared__ char lds[65536];
  const int t = threadIdx.x, l = t & 63, w = t >> 6;
  char* Ps = lds + 49152 + w * 4096;
  const int b = blockIdx.z, h = blockIdx.y;
  const int q0 = blockIdx.x * 128 + w * 32;
  const size_t seq0 = (size_t)b * 2048;
  const float LOG2E = 1.4426950408889634f;

  // Q fragments (A-operand), pre-scaled by log2(e)
  bf16x8 qf[2][2];
  #pragma unroll
  for (int mi = 0; mi < 2; ++mi)
    #pragma unroll
    for (int ks = 0; ks < 2; ++ks) {
      int row = q0 + mi * 16 + (l & 15);
      int col = ks * 32 + 8 * (l >> 4);
      bf16x8 raw = *(const bf16x8*)(qkv + (seq0 + row) * 3072 + h * 192 + col);
      #pragma unroll
      for (int j = 0; j < 8; ++j) {
        unsigned int u = ((unsigned int)(unsigned short)raw[j]) << 16;
        float f = __builtin_bit_cast(float, u) * LOG2E;
        qf[mi][ks][j] = (short)f2bf(f);
      }
    }

  // K: global_load_lds, dest linear, source pre-XOR-swizzled.
  // 128 rows/group: i<4 (proven i<2 pattern extended; same swizzle per row).
  auto k_issue = [&](int kv0, char* Kd) {
    #pragma unroll
    for (int i = 0; i < 4; ++i) {
      int row = i * 32 + w * 8 + (l >> 3);
      int cl = (l & 7) ^ (l >> 3);
      const char* src = (const char*)(qkv + (seq0 + kv0 + row) * 3072 + h * 192 + 64 + cl * 8);
      __builtin_amdgcn_global_load_lds(
          (const __attribute__((address_space(1))) uint32_t*)src,
          (__attribute__((address_space(3))) uint32_t*)(Kd + w * 1024 + i * 4096),
          16, 0, 0);
    }
  };
  // V: reg-stage + transposed scatter at permuted position p = 4*(kv&15)+(kv>>4).
  // Two 64-row sub-tiles per group; single buffer, written between barriers.
  const int vkv = t & 63, vdg = t >> 6;
  const int vp = 4 * (vkv & 15) + (vkv >> 4);
  const int vwithin = (2 * vp) & 15;
  const int vchunk = vp >> 3;
  union { uint4 q[4]; unsigned short s[32]; } vreg;
  auto v_issue = [&](int kv0) {
    #pragma unroll
    for (int sb = 0; sb < 2; ++sb) {
      const __hip_bfloat16* src =
          qkv + (seq0 + kv0 + sb * 64 + vkv) * 3072 + h * 192 + 128 + vdg * 16;
      vreg.q[sb * 2]     = *(const uint4*)(src);
      vreg.q[sb * 2 + 1] = *(const uint4*)(src + 8);
    }
  };
  auto v_write = [&](char* Vd) {
    #pragma unroll
    for (int sb = 0; sb < 2; ++sb)
      #pragma unroll
      for (int j = 0; j < 16; ++j) {
        int d = vdg * 16 + j;
        *(unsigned short*)(Vd + sb * 8192 + d * 128 + ((vchunk ^ (d & 7)) << 4) + vwithin) =
            vreg.s[sb * 16 + j];
      }
  };

  f32x4 O[2][4] = {};
  float m_run[2][4], lp[2][4];   // lp = per-lane partial of l (deferred reduce)
  #pragma unroll
  for (int mi = 0; mi < 2; ++mi)
    #pragma unroll
    for (int r = 0; r < 4; ++r) { m_run[mi][r] = -1e30f; lp[mi][r] = 0.0f; }

  k_issue(0, lds);
  v_issue(0);
  v_write(lds + 32768);
  __syncthreads();

  for (int g = 0; g < 16; ++g) {
    const int cur = g & 1, nxt = cur ^ 1;
    const char* Kg = lds + cur * 16384;
    const char* Vg = lds + 32768;
    if (g < 15) {
      k_issue((g + 1) * 128, lds + nxt * 16384);
      v_issue((g + 1) * 128);
    }

    #pragma unroll
    for (int sb = 0; sb < 2; ++sb) {
      const char* Kc = Kg + sb * 8192;
      const char* Vc = Vg + sb * 8192;

      // ---- S = Q K^T ----
      f32x4 S[2][4] = {};
      __builtin_amdgcn_s_setprio(1);
      #pragma unroll
      for (int ni = 0; ni < 4; ++ni) {
        int kvr = ni * 16 + (l & 15);
        #pragma unroll
        for (int ks = 0; ks < 2; ++ks) {
          bf16x8 kf = *(const bf16x8*)(Kc + kvr * 128 + (((ks * 4 + (l >> 4)) ^ (kvr & 7)) << 4));
          #pragma unroll
          for (int mi = 0; mi < 2; ++mi)
            S[mi][ni] = __builtin_amdgcn_mfma_f32_16x16x32_bf16(qf[mi][ks], kf, S[mi][ni], 0, 0, 0);
        }
      }
      __builtin_amdgcn_s_setprio(0);

      // ---- online softmax (exp2 domain) + packed P write ----
      float tm[2][4];
      bool ok = true;
      #pragma unroll
      for (int mi = 0; mi < 2; ++mi)
        #pragma unroll
        for (int r = 0; r < 4; ++r) {
          float a = fmaxf(fmaxf(S[mi][0][r], S[mi][1][r]), fmaxf(S[mi][2][r], S[mi][3][r]));
          tm[mi][r] = a;
          ok = ok && (a <= m_run[mi][r] + 11.0f);
        }
      const int c = l & 15;
      if (__all(ok)) {
        #pragma unroll
        for (int mi = 0; mi < 2; ++mi)
          #pragma unroll
          for (int r = 0; r < 4; ++r) {
            float mn = m_run[mi][r];
            float p0 = __builtin_amdgcn_exp2f(S[mi][0][r] - mn);
            float p1 = __builtin_amdgcn_exp2f(S[mi][1][r] - mn);
            float p2 = __builtin_amdgcn_exp2f(S[mi][2][r] - mn);
            float p3 = __builtin_amdgcn_exp2f(S[mi][3][r] - mn);
            lp[mi][r] += (p0 + p1) + (p2 + p3);
            uint32_t d0, d1;
            asm("v_cvt_pk_bf16_f32 %0, %1, %2" : "=v"(d0) : "v"(p0), "v"(p1));
            asm("v_cvt_pk_bf16_f32 %0, %1, %2" : "=v"(d1) : "v"(p2), "v"(p3));
            uint2 pk; pk.x = d0; pk.y = d1;
            int q = mi * 16 + (l >> 4) * 4 + r;
            *(uint2*)(Ps + q * 128 + ((((c >> 1) ^ (q & 7))) << 4) + ((c & 1) << 3)) = pk;
          }
      } else {
        #pragma unroll
        for (int mi = 0; mi < 2; ++mi)
          #pragma unroll
          for (int r = 0; r < 4; ++r) {
            float mo = m_run[mi][r];
            float mn = fmaxf(mo, rowmax16(tm[mi][r]));   // full row max (slow path only)
            float sc = __builtin_amdgcn_exp2f(mo - mn);
            m_run[mi][r] = mn;
            float p0 = __builtin_amdgcn_exp2f(S[mi][0][r] - mn);
            float p1 = __builtin_amdgcn_exp2f(S[mi][1][r] - mn);
            float p2 = __builtin_amdgcn_exp2f(S[mi][2][r] - mn);
            float p3 = __builtin_amdgcn_exp2f(S[mi][3][r] - mn);
            lp[mi][r] = lp[mi][r] * sc + (p0 + p1) + (p2 + p3);
            O[mi][0][r] *= sc; O[mi][1][r] *= sc; O[mi][2][r] *= sc; O[mi][3][r] *= sc;
            uint32_t d0, d1;
            asm("v_cvt_pk_bf16_f32 %0, %1, %2" : "=v"(d0) : "v"(p0), "v"(p1));
            asm("v_cvt_pk_bf16_f32 %0, %1, %2" : "=v"(d1) : "v"(p2), "v"(p3));
            uint2 pk; pk.x = d0; pk.y = d1;
            int q = mi * 16 + (l >> 4) * 4 + r;
            *(uint2*)(Ps + q * 128 + ((((c >> 1) ^ (q & 7))) << 4) + ((c & 1) << 3)) = pk;
          }
      }

      // ---- O += P V  (positions are permuted identically on P and V) ----
      bf16x8 pa[2][2];
      #pragma unroll
      for (int mi = 0; mi < 2; ++mi) {
        int q = mi * 16 + (l & 15);
        #pragma unroll
        for (int ks = 0; ks < 2; ++ks)
          pa[mi][ks] = *(const bf16x8*)(Ps + q * 128 + (((ks * 4 + (l >> 4)) ^ (q & 7)) << 4));
      }
      __builtin_amdgcn_s_setprio(1);
      #pragma unroll
      for (int ni = 0; ni < 4; ++ni) {
        int dv = ni * 16 + (l & 15);
        #pragma unroll
        for (int ks = 0; ks < 2; ++ks) {
          bf16x8 vf = *(const bf16x8*)(Vc + dv * 128 + (((ks * 4 + (l >> 4)) ^ (dv & 7)) << 4));
          #pragma unroll
          for (int mi = 0; mi < 2; ++mi)
            O[mi][ni] = __builtin_amdgcn_mfma_f32_16x16x32_bf16(pa[mi][ks], vf, O[mi][ni], 0, 0, 0);
        }
      }
      __builtin_amdgcn_s_setprio(0);
    }

    __syncthreads();                    // all waves done reading V(g) (drains prefetch too)
    if (g < 15) v_write(lds + 32768);
    __syncthreads();                    // V(g+1) visible to all waves
  }

  #pragma unroll
  for (int mi = 0; mi < 2; ++mi) {
    #pragma unroll
    for (int r = 0; r < 4; ++r) {
      float inv = 1.0f / rowsum16(lp[mi][r]);   // single deferred 16-lane reduce
      int row = q0 + mi * 16 + (l >> 4) * 4 + r;
      #pragma unroll
      for (int ni = 0; ni < 4; ++ni) {
        int col = h * 64 + ni * 16 + (l & 15);
        *(unsigned short*)((char*)nv + (((seq0 + row) * 1024 + col)) * 2) =
            f2bf(O[mi][ni][r] * inv);
      }
    }
  }
}

// =================== LayerNorm (in-place on d_out, row = 1024 fp32) ===================
__global__ __launch_bounds__(256) void k_ln(float* __restrict__ io) {
  int row = blockIdx.x, t = threadIdx.x;
  float* p = io + (size_t)row * 1024;
  float4 v = *(const float4*)(p + t * 4);
  float s = v.x + v.y + v.z + v.w;
  float q = v.x * v.x + v.y * v.y + v.z * v.z + v.w * v.w;
  #pragma unroll
  for (int off = 32; off > 0; off >>= 1) { s += __shfl_xor(s, off); q += __shfl_xor(q, off); }
  __shared__ float red[8];
  if ((t & 63) == 0) { red[t >> 6] = s; red[4 + (t >> 6)] = q; }
  __syncthreads();
  s = red[0] + red[1] + red[2] + red[3];
  q = red[4] + red[5] + red[6] + red[7];
  float mu = s * (1.0f / 1024.0f);
  float var = q * (1.0f / 1024.0f) - mu * mu;
  float rs = rsqrtf(var + 1e-5f);
  float4 o;
  o.x = (v.x - mu) * rs; o.y = (v.y - mu) * rs; o.z = (v.z - mu) * rs; o.w = (v.w - mu) * rs;
  *(float4*)(p + t * 4) = o;
}

// =================== launch ===================
extern "C" void kernel_launch(void* const* d_in, const int* in_sizes, int n_in,
                              void* d_out, int out_size, void* d_ws, size_t ws_size,
                              hipStream_t stream) {
  const float* x    = (const float*)d_in[0];   // [4,2048,1024]
  const float* Wfc  = (const float*)d_in[1];   // [1024,3072]
  const float* bfc  = (const float*)d_in[2];   // [3072]
  const float* Wout = (const float*)d_in[3];   // [1024,1024]
  const float* bout = (const float*)d_in[4];   // [1024]
  float* out = (float*)d_out;                  // [4,2048,1024] fp32

  char* ws = (char*)d_ws;
  __hip_bfloat16* xb   = (__hip_bfloat16*)(ws);                 // 16,777,216 B
  __hip_bfloat16* wfct = (__hip_bfloat16*)(ws + 16777216);      //  6,291,456 B [3072][1024]
  __hip_bfloat16* wot  = (__hip_bfloat16*)(ws + 23068672);      //  2,097,152 B [1024][1024]
  __hip_bfloat16* qkvb = (__hip_bfloat16*)(ws + 25165824);      // 50,331,648 B [8192][3072]
  __hip_bfloat16* nvb  = (__hip_bfloat16*)(ws + 75497472);      // 16,777,216 B [8192][1024]

  k_cvt_bf16<<<4096, 256, 0, stream>>>(x, xb);
  k_transpose_bf16<<<dim3(96, 32), 256, 0, stream>>>(Wfc, wfct, 1024, 3072);
  k_transpose_bf16<<<dim3(32, 32), 256, 0, stream>>>(Wout, wot, 1024, 1024);
  k_gemm_fc<<<dim3(24, 64), 256, 0, stream>>>(xb, wfct, bfc, qkvb, 8192, 3072, 1024);
  k_attn<<<dim3(16, 16, 4), 256, 0, stream>>>(qkvb, nvb);
  k_gemm_out<<<dim3(8, 64), 256, 0, stream>>>(nvb, wot, bout, x, out, 8192, 1024, 1024);
  k_ln<<<8192, 256, 0, stream>>>(out);
}

// Round 13
// 273.061 us; speedup vs baseline: 1.3766x; 1.3766x over previous
//
#include <hip/hip_runtime.h>
#include <hip/hip_bf16.h>
#include <stdint.h>

typedef float  f32x4  __attribute__((ext_vector_type(4)));
typedef short  bf16x8 __attribute__((ext_vector_type(8)));

__device__ __forceinline__ unsigned short f2bf(float f) {
  union { __hip_bfloat16 b; unsigned short u; } cv;
  cv.b = __float2bfloat16(f);
  return cv.u;
}

// ---- DPP 16-lane rotate-reductions (row_ror:n = 0x120|n), full-rate VALU ----
template <int CTRL>
__device__ __forceinline__ float dpp_mv(float x) {
  int v = __builtin_bit_cast(int, x);
  v = __builtin_amdgcn_update_dpp(v, v, CTRL, 0xF, 0xF, false);
  return __builtin_bit_cast(float, v);
}
__device__ __forceinline__ float rowmax16(float x) {
  x = fmaxf(x, dpp_mv<0x121>(x));
  x = fmaxf(x, dpp_mv<0x122>(x));
  x = fmaxf(x, dpp_mv<0x124>(x));
  x = fmaxf(x, dpp_mv<0x128>(x));
  return x;
}
__device__ __forceinline__ float rowsum16(float x) {
  x += dpp_mv<0x121>(x);
  x += dpp_mv<0x122>(x);
  x += dpp_mv<0x124>(x);
  x += dpp_mv<0x128>(x);
  return x;
}

// =================== elementwise converts ===================
// 8 floats/thread: 2x float4 load -> one 16B bf16x8 store (grid 4096).
__global__ __launch_bounds__(256) void k_cvt_bf16(const float* __restrict__ in,
                                                  __hip_bfloat16* __restrict__ out) {
  size_t i = (size_t)blockIdx.x * 256 + threadIdx.x;
  float4 a = *(const float4*)(in + i * 8);
  float4 b = *(const float4*)(in + i * 8 + 4);
  bf16x8 o;
  o[0] = (short)f2bf(a.x); o[1] = (short)f2bf(a.y);
  o[2] = (short)f2bf(a.z); o[3] = (short)f2bf(a.w);
  o[4] = (short)f2bf(b.x); o[5] = (short)f2bf(b.y);
  o[6] = (short)f2bf(b.z); o[7] = (short)f2bf(b.w);
  *(bf16x8*)(out + i * 8) = o;
}

// in [K][N] fp32 -> out [N][K] bf16 (32x32 LDS tile transpose)
__global__ __launch_bounds__(256) void k_transpose_bf16(const float* __restrict__ in,
                                                        __hip_bfloat16* __restrict__ out,
                                                        int K, int N) {
  __shared__ float tile[32][33];
  int t = threadIdx.x;
  int k0 = blockIdx.y * 32, n0 = blockIdx.x * 32;
  {
    int kl = t >> 3, nl = (t & 7) * 4;
    float4 v = *(const float4*)(in + (size_t)(k0 + kl) * N + n0 + nl);
    tile[kl][nl] = v.x; tile[kl][nl + 1] = v.y; tile[kl][nl + 2] = v.z; tile[kl][nl + 3] = v.w;
  }
  __syncthreads();
  {
    int nl = t >> 3, kl = (t & 7) * 4;
    union { short4 s; unsigned short u[4]; } o;
    #pragma unroll
    for (int i = 0; i < 4; ++i) o.u[i] = f2bf(tile[kl + i][nl]);
    *(short4*)(out + (size_t)(n0 + nl) * K + k0 + kl) = o.s;
  }
}

// =================== GEMM (A row-major, Bt = B^T row-major, both bf16) ===================
__device__ __forceinline__ void stage128x32(const __hip_bfloat16* gsrc_row0, int ld_elem,
                                            char* lds_tile, int t) {
  int w = t >> 6, lam = t & 63;
  #pragma unroll
  for (int i = 0; i < 2; ++i) {
    int idx = w * 1024 + i * 4096 + lam * 16;
    int row = idx >> 6;
    int cph = (idx >> 4) & 3;
    int csrc = cph ^ ((row >> 1) & 3);
    const char* src = (const char*)(gsrc_row0 + (size_t)row * ld_elem) + csrc * 16;
    __builtin_amdgcn_global_load_lds(
        (const __attribute__((address_space(1))) uint32_t*)src,
        (__attribute__((address_space(3))) uint32_t*)(lds_tile + w * 1024 + i * 4096),
        16, 0, 0);
  }
}

__device__ __forceinline__ bf16x8 frag64(const char* tile, int row, int chunk) {
  int c = chunk ^ ((row >> 1) & 3);
  return *(const bf16x8*)(tile + row * 64 + c * 16);
}

// C = swish(A @ Bt^T + bias) -> bf16
__global__ __launch_bounds__(256) void k_gemm_fc(const __hip_bfloat16* __restrict__ A,
                                                 const __hip_bfloat16* __restrict__ Bt,
                                                 const float* __restrict__ bias,
                                                 __hip_bfloat16* __restrict__ C,
                                                 int M, int N, int K) {
  __shared__ char lds[16384];
  char* As = lds; char* Bs = lds + 8192;
  const int t = threadIdx.x, l = t & 63, w = t >> 6;
  const int bm0 = blockIdx.y * 128, bn0 = blockIdx.x * 128;
  const int wm = (w >> 1) * 64, wn = (w & 1) * 64;
  f32x4 acc[4][4] = {};
  for (int kt = 0; kt < K; kt += 32) {
    stage128x32(A + (size_t)bm0 * K + kt, K, As, t);
    stage128x32(Bt + (size_t)bn0 * K + kt, K, Bs, t);
    __syncthreads();
    bf16x8 af[4], bfr[4];
    #pragma unroll
    for (int mi = 0; mi < 4; ++mi) af[mi] = frag64(As, wm + mi * 16 + (l & 15), l >> 4);
    #pragma unroll
    for (int ni = 0; ni < 4; ++ni) bfr[ni] = frag64(Bs, wn + ni * 16 + (l & 15), l >> 4);
    #pragma unroll
    for (int mi = 0; mi < 4; ++mi)
      #pragma unroll
      for (int ni = 0; ni < 4; ++ni)
        acc[mi][ni] = __builtin_amdgcn_mfma_f32_16x16x32_bf16(af[mi], bfr[ni], acc[mi][ni], 0, 0, 0);
    __syncthreads();
  }
  #pragma unroll
  for (int mi = 0; mi < 4; ++mi)
    #pragma unroll
    for (int ni = 0; ni < 4; ++ni)
      #pragma unroll
      for (int r = 0; r < 4; ++r) {
        int row = bm0 + wm + mi * 16 + (l >> 4) * 4 + r;
        int col = bn0 + wn + ni * 16 + (l & 15);
        float v = acc[mi][ni][r] + bias[col];
        v = v / (1.0f + __expf(-v));
        *(unsigned short*)((char*)C + ((size_t)row * N + col) * 2) = f2bf(v);
      }
}

// C = swish(A @ Bt^T + bias) + X  -> fp32
__global__ __launch_bounds__(256) void k_gemm_out(const __hip_bfloat16* __restrict__ A,
                                                  const __hip_bfloat16* __restrict__ Bt,
                                                  const float* __restrict__ bias,
                                                  const float* __restrict__ X,
                                                  float* __restrict__ C,
                                                  int M, int N, int K) {
  __shared__ char lds[16384];
  char* As = lds; char* Bs = lds + 8192;
  const int t = threadIdx.x, l = t & 63, w = t >> 6;
  const int bm0 = blockIdx.y * 128, bn0 = blockIdx.x * 128;
  const int wm = (w >> 1) * 64, wn = (w & 1) * 64;
  f32x4 acc[4][4] = {};
  for (int kt = 0; kt < K; kt += 32) {
    stage128x32(A + (size_t)bm0 * K + kt, K, As, t);
    stage128x32(Bt + (size_t)bn0 * K + kt, K, Bs, t);
    __syncthreads();
    bf16x8 af[4], bfr[4];
    #pragma unroll
    for (int mi = 0; mi < 4; ++mi) af[mi] = frag64(As, wm + mi * 16 + (l & 15), l >> 4);
    #pragma unroll
    for (int ni = 0; ni < 4; ++ni) bfr[ni] = frag64(Bs, wn + ni * 16 + (l & 15), l >> 4);
    #pragma unroll
    for (int mi = 0; mi < 4; ++mi)
      #pragma unroll
      for (int ni = 0; ni < 4; ++ni)
        acc[mi][ni] = __builtin_amdgcn_mfma_f32_16x16x32_bf16(af[mi], bfr[ni], acc[mi][ni], 0, 0, 0);
    __syncthreads();
  }
  #pragma unroll
  for (int mi = 0; mi < 4; ++mi)
    #pragma unroll
    for (int ni = 0; ni < 4; ++ni)
      #pragma unroll
      for (int r = 0; r < 4; ++r) {
        int row = bm0 + wm + mi * 16 + (l >> 4) * 4 + r;
        int col = bn0 + wn + ni * 16 + (l & 15);
        float v = acc[mi][ni][r] + bias[col];
        v = v / (1.0f + __expf(-v));
        v += X[(size_t)row * N + col];
        C[(size_t)row * N + col] = v;
      }
}

// =================== flash attention v3.12 (R8 body + XCD-chunked block map) ===================
// Body/barriers/LDS = byte-exact R8/R11 (155 µs proven).  ONLY change: grid is
// 1-D (1024) and the work ID is XCD-chunk-swizzled (T1):
//   wgid = (bid & 7)*128 + (bid >> 3)    (bijective; 1024 % 8 == 0)
// so each XCD's round-robin share {bid ≡ x (mod 8)} maps to a CONTIGUOUS
// 128-wgid chunk = 8 (b,h) groups.  The 16 blocks sharing one (b,h) (same
// 512 KB K/V) then land on ONE XCD: resident K/V working set per XCD drops
// ~16 MB -> ~2 MB < 4 MB L2, turning K/V re-reads into L2 hits and shrinking
// the vmcnt(0)-drain stalls at the two per-tile barriers.
// LDS CLIFF (R12): 64 KB LDS -> 1 block/CU (occupancy 21%->11.6%, 1.7x slower).
// Keep attn LDS <= 48 KB.
// POISONED (empirically fail on HW; no disasm here — do not retry):
//   * m-init-0 + C-init fold of -m into QK^T MFMA      (R4 6.0, R5 1.55)
//   * l via ones-column MFMA accumulation              (R7 6.52)
//   * single-barrier V-dbuf merged with this softmax   (R10 0.203)
//   * __launch_bounds__ min-waves hint                 (R2 spill)
// Also: 16-row warps regressed (R9); OccupancyPercent reads ~0.5x theoretical.
__global__ __launch_bounds__(256) void k_attn(const __hip_bfloat16* __restrict__ qkv,
                                              __hip_bfloat16* __restrict__ nv) {
  __shared__ char lds[40960];
  const int t = threadIdx.x, l = t & 63, w = t >> 6;
  char* Ps = lds + 24576 + w * 4096;
  const int bid = blockIdx.x;
  const int wgid = (bid & 7) * 128 + (bid >> 3);   // XCD-chunked, bijective
  const int qi = wgid & 15;
  const int h  = (wgid >> 4) & 15;
  const int b  = wgid >> 8;
  const int q0 = qi * 128 + w * 32;
  const size_t seq0 = (size_t)b * 2048;
  const float LOG2E = 1.4426950408889634f;

  // Q fragments (A-operand), pre-scaled by log2(e)
  bf16x8 qf[2][2];
  #pragma unroll
  for (int mi = 0; mi < 2; ++mi)
    #pragma unroll
    for (int ks = 0; ks < 2; ++ks) {
      int row = q0 + mi * 16 + (l & 15);
      int col = ks * 32 + 8 * (l >> 4);
      bf16x8 raw = *(const bf16x8*)(qkv + (seq0 + row) * 3072 + h * 192 + col);
      #pragma unroll
      for (int j = 0; j < 8; ++j) {
        unsigned int u = ((unsigned int)(unsigned short)raw[j]) << 16;
        float f = __builtin_bit_cast(float, u) * LOG2E;
        qf[mi][ks][j] = (short)f2bf(f);
      }
    }

  // K: global_load_lds, dest linear, source pre-XOR-swizzled. Double-buffered.
  auto k_issue = [&](int kv0, char* Kd) {
    #pragma unroll
    for (int i = 0; i < 2; ++i) {
      int row = i * 32 + w * 8 + (l >> 3);
      int cl = (l & 7) ^ (l >> 3);
      const char* src = (const char*)(qkv + (seq0 + kv0 + row) * 3072 + h * 192 + 64 + cl * 8);
      __builtin_amdgcn_global_load_lds(
          (const __attribute__((address_space(1))) uint32_t*)src,
          (__attribute__((address_space(3))) uint32_t*)(Kd + w * 1024 + i * 4096),
          16, 0, 0);
    }
  };
  // V: reg-stage + transposed scatter at permuted position p = 4*(kv&15)+(kv>>4).
  // Single buffer: write happens between the two end-of-iteration barriers.
  const int vkv = t & 63, vdg = t >> 6;
  const int vp = 4 * (vkv & 15) + (vkv >> 4);
  const int vwithin = (2 * vp) & 15;
  const int vchunk = vp >> 3;
  union { uint4 q[2]; unsigned short s[16]; } vreg;
  auto v_issue = [&](int kv0) {
    const __hip_bfloat16* src = qkv + (seq0 + kv0 + vkv) * 3072 + h * 192 + 128 + vdg * 16;
    vreg.q[0] = *(const uint4*)(src);
    vreg.q[1] = *(const uint4*)(src + 8);
  };
  auto v_write = [&](char* Vd) {
    #pragma unroll
    for (int j = 0; j < 16; ++j) {
      int d = vdg * 16 + j;
      *(unsigned short*)(Vd + d * 128 + ((vchunk ^ (d & 7)) << 4) + vwithin) = vreg.s[j];
    }
  };

  f32x4 O[2][4] = {};
  float m_run[2][4], lp[2][4];   // lp = per-lane partial of l (deferred reduce)
  #pragma unroll
  for (int mi = 0; mi < 2; ++mi)
    #pragma unroll
    for (int r = 0; r < 4; ++r) { m_run[mi][r] = -1e30f; lp[mi][r] = 0.0f; }

  k_issue(0, lds);
  v_issue(0);
  v_write(lds + 16384);
  __syncthreads();

  for (int tIdx = 0; tIdx < 32; ++tIdx) {
    const int cur = tIdx & 1, nxt = cur ^ 1;
    const char* Kc = lds + cur * 8192;
    const char* Vc = lds + 16384;
    if (tIdx < 31) {
      k_issue((tIdx + 1) * 64, lds + nxt * 8192);
      v_issue((tIdx + 1) * 64);
    }

    // ---- S = Q K^T ----
    f32x4 S[2][4] = {};
    __builtin_amdgcn_s_setprio(1);
    #pragma unroll
    for (int ni = 0; ni < 4; ++ni) {
      int kvr = ni * 16 + (l & 15);
      #pragma unroll
      for (int ks = 0; ks < 2; ++ks) {
        bf16x8 kf = *(const bf16x8*)(Kc + kvr * 128 + (((ks * 4 + (l >> 4)) ^ (kvr & 7)) << 4));
        #pragma unroll
        for (int mi = 0; mi < 2; ++mi)
          S[mi][ni] = __builtin_amdgcn_mfma_f32_16x16x32_bf16(qf[mi][ks], kf, S[mi][ni], 0, 0, 0);
      }
    }
    __builtin_amdgcn_s_setprio(0);

    // ---- online softmax (exp2 domain) + packed P write ----
    // tm holds the LANE-LOCAL 4-column partial; check equivalent to the
    // row-max check under __all (m_run uniform per 16-lane row group).
    float tm[2][4];
    bool ok = true;
    #pragma unroll
    for (int mi = 0; mi < 2; ++mi)
      #pragma unroll
      for (int r = 0; r < 4; ++r) {
        float a = fmaxf(fmaxf(S[mi][0][r], S[mi][1][r]), fmaxf(S[mi][2][r], S[mi][3][r]));
        tm[mi][r] = a;
        ok = ok && (a <= m_run[mi][r] + 11.0f);
      }
    const int c = l & 15;
    if (__all(ok)) {
      // defer: m unchanged, no O rescale; lp accumulates lane-local partial
      #pragma unroll
      for (int mi = 0; mi < 2; ++mi)
        #pragma unroll
        for (int r = 0; r < 4; ++r) {
          float mn = m_run[mi][r];
          float p0 = __builtin_amdgcn_exp2f(S[mi][0][r] - mn);
          float p1 = __builtin_amdgcn_exp2f(S[mi][1][r] - mn);
          float p2 = __builtin_amdgcn_exp2f(S[mi][2][r] - mn);
          float p3 = __builtin_amdgcn_exp2f(S[mi][3][r] - mn);
          lp[mi][r] += (p0 + p1) + (p2 + p3);
          uint32_t d0, d1;
          asm("v_cvt_pk_bf16_f32 %0, %1, %2" : "=v"(d0) : "v"(p0), "v"(p1));
          asm("v_cvt_pk_bf16_f32 %0, %1, %2" : "=v"(d1) : "v"(p2), "v"(p3));
          uint2 pk; pk.x = d0; pk.y = d1;
          int q = mi * 16 + (l >> 4) * 4 + r;
          *(uint2*)(Ps + q * 128 + ((((c >> 1) ^ (q & 7))) << 4) + ((c & 1) << 3)) = pk;
        }
    } else {
      #pragma unroll
      for (int mi = 0; mi < 2; ++mi)
        #pragma unroll
        for (int r = 0; r < 4; ++r) {
          float mo = m_run[mi][r];
          float mn = fmaxf(mo, rowmax16(tm[mi][r]));   // full row max (slow path only)
          float sc = __builtin_amdgcn_exp2f(mo - mn);
          m_run[mi][r] = mn;
          float p0 = __builtin_amdgcn_exp2f(S[mi][0][r] - mn);
          float p1 = __builtin_amdgcn_exp2f(S[mi][1][r] - mn);
          float p2 = __builtin_amdgcn_exp2f(S[mi][2][r] - mn);
          float p3 = __builtin_amdgcn_exp2f(S[mi][3][r] - mn);
          lp[mi][r] = lp[mi][r] * sc + (p0 + p1) + (p2 + p3);
          O[mi][0][r] *= sc; O[mi][1][r] *= sc; O[mi][2][r] *= sc; O[mi][3][r] *= sc;
          uint32_t d0, d1;
          asm("v_cvt_pk_bf16_f32 %0, %1, %2" : "=v"(d0) : "v"(p0), "v"(p1));
          asm("v_cvt_pk_bf16_f32 %0, %1, %2" : "=v"(d1) : "v"(p2), "v"(p3));
          uint2 pk; pk.x = d0; pk.y = d1;
          int q = mi * 16 + (l >> 4) * 4 + r;
          *(uint2*)(Ps + q * 128 + ((((c >> 1) ^ (q & 7))) << 4) + ((c & 1) << 3)) = pk;
        }
    }

    // ---- O += P V  (positions are permuted identically on P and V) ----
    bf16x8 pa[2][2];
    #pragma unroll
    for (int mi = 0; mi < 2; ++mi) {
      int q = mi * 16 + (l & 15);
      #pragma unroll
      for (int ks = 0; ks < 2; ++ks)
        pa[mi][ks] = *(const bf16x8*)(Ps + q * 128 + (((ks * 4 + (l >> 4)) ^ (q & 7)) << 4));
    }
    __builtin_amdgcn_s_setprio(1);
    #pragma unroll
    for (int ni = 0; ni < 4; ++ni) {
      int dv = ni * 16 + (l & 15);
      #pragma unroll
      for (int ks = 0; ks < 2; ++ks) {
        bf16x8 vf = *(const bf16x8*)(Vc + dv * 128 + (((ks * 4 + (l >> 4)) ^ (dv & 7)) << 4));
        #pragma unroll
        for (int mi = 0; mi < 2; ++mi)
          O[mi][ni] = __builtin_amdgcn_mfma_f32_16x16x32_bf16(pa[mi][ks], vf, O[mi][ni], 0, 0, 0);
      }
    }
    __builtin_amdgcn_s_setprio(0);

    __syncthreads();                    // all waves done reading V(t) (drains prefetch too)
    if (tIdx < 31) v_write(lds + 16384);
    __syncthreads();                    // V(t+1) visible to all waves
  }

  #pragma unroll
  for (int mi = 0; mi < 2; ++mi) {
    #pragma unroll
    for (int r = 0; r < 4; ++r) {
      float inv = 1.0f / rowsum16(lp[mi][r]);   // single deferred 16-lane reduce
      int row = q0 + mi * 16 + (l >> 4) * 4 + r;
      #pragma unroll
      for (int ni = 0; ni < 4; ++ni) {
        int col = h * 64 + ni * 16 + (l & 15);
        *(unsigned short*)((char*)nv + (((seq0 + row) * 1024 + col)) * 2) =
            f2bf(O[mi][ni][r] * inv);
      }
    }
  }
}

// =================== LayerNorm (in-place on d_out, row = 1024 fp32) ===================
__global__ __launch_bounds__(256) void k_ln(float* __restrict__ io) {
  int row = blockIdx.x, t = threadIdx.x;
  float* p = io + (size_t)row * 1024;
  float4 v = *(const float4*)(p + t * 4);
  float s = v.x + v.y + v.z + v.w;
  float q = v.x * v.x + v.y * v.y + v.z * v.z + v.w * v.w;
  #pragma unroll
  for (int off = 32; off > 0; off >>= 1) { s += __shfl_xor(s, off); q += __shfl_xor(q, off); }
  __shared__ float red[8];
  if ((t & 63) == 0) { red[t >> 6] = s; red[4 + (t >> 6)] = q; }
  __syncthreads();
  s = red[0] + red[1] + red[2] + red[3];
  q = red[4] + red[5] + red[6] + red[7];
  float mu = s * (1.0f / 1024.0f);
  float var = q * (1.0f / 1024.0f) - mu * mu;
  float rs = rsqrtf(var + 1e-5f);
  float4 o;
  o.x = (v.x - mu) * rs; o.y = (v.y - mu) * rs; o.z = (v.z - mu) * rs; o.w = (v.w - mu) * rs;
  *(float4*)(p + t * 4) = o;
}

// =================== launch ===================
extern "C" void kernel_launch(void* const* d_in, const int* in_sizes, int n_in,
                              void* d_out, int out_size, void* d_ws, size_t ws_size,
                              hipStream_t stream) {
  const float* x    = (const float*)d_in[0];   // [4,2048,1024]
  const float* Wfc  = (const float*)d_in[1];   // [1024,3072]
  const float* bfc  = (const float*)d_in[2];   // [3072]
  const float* Wout = (const float*)d_in[3];   // [1024,1024]
  const float* bout = (const float*)d_in[4];   // [1024]
  float* out = (float*)d_out;                  // [4,2048,1024] fp32

  char* ws = (char*)d_ws;
  __hip_bfloat16* xb   = (__hip_bfloat16*)(ws);                 // 16,777,216 B
  __hip_bfloat16* wfct = (__hip_bfloat16*)(ws + 16777216);      //  6,291,456 B [3072][1024]
  __hip_bfloat16* wot  = (__hip_bfloat16*)(ws + 23068672);      //  2,097,152 B [1024][1024]
  __hip_bfloat16* qkvb = (__hip_bfloat16*)(ws + 25165824);      // 50,331,648 B [8192][3072]
  __hip_bfloat16* nvb  = (__hip_bfloat16*)(ws + 75497472);      // 16,777,216 B [8192][1024]

  k_cvt_bf16<<<4096, 256, 0, stream>>>(x, xb);
  k_transpose_bf16<<<dim3(96, 32), 256, 0, stream>>>(Wfc, wfct, 1024, 3072);
  k_transpose_bf16<<<dim3(32, 32), 256, 0, stream>>>(Wout, wot, 1024, 1024);
  k_gemm_fc<<<dim3(24, 64), 256, 0, stream>>>(xb, wfct, bfc, qkvb, 8192, 3072, 1024);
  k_attn<<<1024, 256, 0, stream>>>(qkvb, nvb);
  k_gemm_out<<<dim3(8, 64), 256, 0, stream>>>(nvb, wot, bout, x, out, 8192, 1024, 1024);
  k_ln<<<8192, 256, 0, stream>>>(out);
}

// Round 14
// 270.398 us; speedup vs baseline: 1.3902x; 1.0098x over previous
//
#include <hip/hip_runtime.h>
#include <hip/hip_bf16.h>
#include <stdint.h>

typedef float  f32x4  __attribute__((ext_vector_type(4)));
typedef short  bf16x8 __attribute__((ext_vector_type(8)));

__device__ __forceinline__ unsigned short f2bf(float f) {
  union { __hip_bfloat16 b; unsigned short u; } cv;
  cv.b = __float2bfloat16(f);
  return cv.u;
}

// ---- DPP 16-lane rotate-reductions (row_ror:n = 0x120|n), full-rate VALU ----
template <int CTRL>
__device__ __forceinline__ float dpp_mv(float x) {
  int v = __builtin_bit_cast(int, x);
  v = __builtin_amdgcn_update_dpp(v, v, CTRL, 0xF, 0xF, false);
  return __builtin_bit_cast(float, v);
}
__device__ __forceinline__ float rowmax16(float x) {
  x = fmaxf(x, dpp_mv<0x121>(x));
  x = fmaxf(x, dpp_mv<0x122>(x));
  x = fmaxf(x, dpp_mv<0x124>(x));
  x = fmaxf(x, dpp_mv<0x128>(x));
  return x;
}
__device__ __forceinline__ float rowsum16(float x) {
  x += dpp_mv<0x121>(x);
  x += dpp_mv<0x122>(x);
  x += dpp_mv<0x124>(x);
  x += dpp_mv<0x128>(x);
  return x;
}

// =================== elementwise converts ===================
// 8 floats/thread: 2x float4 load -> one 16B bf16x8 store (grid 4096).
__global__ __launch_bounds__(256) void k_cvt_bf16(const float* __restrict__ in,
                                                  __hip_bfloat16* __restrict__ out) {
  size_t i = (size_t)blockIdx.x * 256 + threadIdx.x;
  float4 a = *(const float4*)(in + i * 8);
  float4 b = *(const float4*)(in + i * 8 + 4);
  bf16x8 o;
  o[0] = (short)f2bf(a.x); o[1] = (short)f2bf(a.y);
  o[2] = (short)f2bf(a.z); o[3] = (short)f2bf(a.w);
  o[4] = (short)f2bf(b.x); o[5] = (short)f2bf(b.y);
  o[6] = (short)f2bf(b.z); o[7] = (short)f2bf(b.w);
  *(bf16x8*)(out + i * 8) = o;
}

// in [K][N] fp32 -> out [N][K] bf16 (32x32 LDS tile transpose)
__global__ __launch_bounds__(256) void k_transpose_bf16(const float* __restrict__ in,
                                                        __hip_bfloat16* __restrict__ out,
                                                        int K, int N) {
  __shared__ float tile[32][33];
  int t = threadIdx.x;
  int k0 = blockIdx.y * 32, n0 = blockIdx.x * 32;
  {
    int kl = t >> 3, nl = (t & 7) * 4;
    float4 v = *(const float4*)(in + (size_t)(k0 + kl) * N + n0 + nl);
    tile[kl][nl] = v.x; tile[kl][nl + 1] = v.y; tile[kl][nl + 2] = v.z; tile[kl][nl + 3] = v.w;
  }
  __syncthreads();
  {
    int nl = t >> 3, kl = (t & 7) * 4;
    union { short4 s; unsigned short u[4]; } o;
    #pragma unroll
    for (int i = 0; i < 4; ++i) o.u[i] = f2bf(tile[kl + i][nl]);
    *(short4*)(out + (size_t)(n0 + nl) * K + k0 + kl) = o.s;
  }
}

// =================== GEMM (A row-major, Bt = B^T row-major, both bf16) ===================
__device__ __forceinline__ void stage128x32(const __hip_bfloat16* gsrc_row0, int ld_elem,
                                            char* lds_tile, int t) {
  int w = t >> 6, lam = t & 63;
  #pragma unroll
  for (int i = 0; i < 2; ++i) {
    int idx = w * 1024 + i * 4096 + lam * 16;
    int row = idx >> 6;
    int cph = (idx >> 4) & 3;
    int csrc = cph ^ ((row >> 1) & 3);
    const char* src = (const char*)(gsrc_row0 + (size_t)row * ld_elem) + csrc * 16;
    __builtin_amdgcn_global_load_lds(
        (const __attribute__((address_space(1))) uint32_t*)src,
        (__attribute__((address_space(3))) uint32_t*)(lds_tile + w * 1024 + i * 4096),
        16, 0, 0);
  }
}

__device__ __forceinline__ bf16x8 frag64(const char* tile, int row, int chunk) {
  int c = chunk ^ ((row >> 1) & 3);
  return *(const bf16x8*)(tile + row * 64 + c * 16);
}

// C = swish(A @ Bt^T + bias) -> bf16
// 1-D grid (1536), XCD-chunked (T1): each XCD's round-robin share maps to a
// contiguous wgid chunk = 8 M-panels x all 24 N-tiles, so A-panels are read
// once per XCD instead of replicated across all 8 L2s.
__global__ __launch_bounds__(256) void k_gemm_fc(const __hip_bfloat16* __restrict__ A,
                                                 const __hip_bfloat16* __restrict__ Bt,
                                                 const float* __restrict__ bias,
                                                 __hip_bfloat16* __restrict__ C,
                                                 int M, int N, int K) {
  __shared__ char lds[16384];
  char* As = lds; char* Bs = lds + 8192;
  const int t = threadIdx.x, l = t & 63, w = t >> 6;
  const int bid = blockIdx.x;
  const int wgid = (bid & 7) * 192 + (bid >> 3);   // bijective: 1536 = 8*192
  const int bm0 = (wgid / 24) * 128, bn0 = (wgid % 24) * 128;
  const int wm = (w >> 1) * 64, wn = (w & 1) * 64;
  f32x4 acc[4][4] = {};
  for (int kt = 0; kt < K; kt += 32) {
    stage128x32(A + (size_t)bm0 * K + kt, K, As, t);
    stage128x32(Bt + (size_t)bn0 * K + kt, K, Bs, t);
    __syncthreads();
    bf16x8 af[4], bfr[4];
    #pragma unroll
    for (int mi = 0; mi < 4; ++mi) af[mi] = frag64(As, wm + mi * 16 + (l & 15), l >> 4);
    #pragma unroll
    for (int ni = 0; ni < 4; ++ni) bfr[ni] = frag64(Bs, wn + ni * 16 + (l & 15), l >> 4);
    #pragma unroll
    for (int mi = 0; mi < 4; ++mi)
      #pragma unroll
      for (int ni = 0; ni < 4; ++ni)
        acc[mi][ni] = __builtin_amdgcn_mfma_f32_16x16x32_bf16(af[mi], bfr[ni], acc[mi][ni], 0, 0, 0);
    __syncthreads();
  }
  #pragma unroll
  for (int mi = 0; mi < 4; ++mi)
    #pragma unroll
    for (int ni = 0; ni < 4; ++ni)
      #pragma unroll
      for (int r = 0; r < 4; ++r) {
        int row = bm0 + wm + mi * 16 + (l >> 4) * 4 + r;
        int col = bn0 + wn + ni * 16 + (l & 15);
        float v = acc[mi][ni][r] + bias[col];
        v = v / (1.0f + __expf(-v));
        *(unsigned short*)((char*)C + ((size_t)row * N + col) * 2) = f2bf(v);
      }
}

// C = swish(A @ Bt^T + bias) + X  -> fp32   (XCD-chunked, grid 512 = 8*64)
__global__ __launch_bounds__(256) void k_gemm_out(const __hip_bfloat16* __restrict__ A,
                                                  const __hip_bfloat16* __restrict__ Bt,
                                                  const float* __restrict__ bias,
                                                  const float* __restrict__ X,
                                                  float* __restrict__ C,
                                                  int M, int N, int K) {
  __shared__ char lds[16384];
  char* As = lds; char* Bs = lds + 8192;
  const int t = threadIdx.x, l = t & 63, w = t >> 6;
  const int bid = blockIdx.x;
  const int wgid = (bid & 7) * 64 + (bid >> 3);    // bijective: 512 = 8*64
  const int bm0 = (wgid / 8) * 128, bn0 = (wgid % 8) * 128;
  const int wm = (w >> 1) * 64, wn = (w & 1) * 64;
  f32x4 acc[4][4] = {};
  for (int kt = 0; kt < K; kt += 32) {
    stage128x32(A + (size_t)bm0 * K + kt, K, As, t);
    stage128x32(Bt + (size_t)bn0 * K + kt, K, Bs, t);
    __syncthreads();
    bf16x8 af[4], bfr[4];
    #pragma unroll
    for (int mi = 0; mi < 4; ++mi) af[mi] = frag64(As, wm + mi * 16 + (l & 15), l >> 4);
    #pragma unroll
    for (int ni = 0; ni < 4; ++ni) bfr[ni] = frag64(Bs, wn + ni * 16 + (l & 15), l >> 4);
    #pragma unroll
    for (int mi = 0; mi < 4; ++mi)
      #pragma unroll
      for (int ni = 0; ni < 4; ++ni)
        acc[mi][ni] = __builtin_amdgcn_mfma_f32_16x16x32_bf16(af[mi], bfr[ni], acc[mi][ni], 0, 0, 0);
    __syncthreads();
  }
  #pragma unroll
  for (int mi = 0; mi < 4; ++mi)
    #pragma unroll
    for (int ni = 0; ni < 4; ++ni)
      #pragma unroll
      for (int r = 0; r < 4; ++r) {
        int row = bm0 + wm + mi * 16 + (l >> 4) * 4 + r;
        int col = bn0 + wn + ni * 16 + (l & 15);
        float v = acc[mi][ni][r] + bias[col];
        v = v / (1.0f + __expf(-v));
        v += X[(size_t)row * N + col];
        C[(size_t)row * N + col] = v;
      }
}

// =================== flash attention v3.12 (R8 body + XCD-chunked block map) ===================
// BYTE-EXACT R13 (passed, 154 µs; FETCH 139->24.7 MB).  R13's A/B proved the
// per-tile drains are NOT memory-latency-bound (FETCH -5.6x, time flat): the
// kernel is bound by its own dependency chain at 2 waves/SIMD TLP.  Breaking
// that requires the poisoned class below — structural plateau for this session.
// LDS CLIFF (R12): 64 KB LDS -> 1 block/CU (occupancy 21%->11.6%, 1.7x slower).
// POISONED (empirically fail on HW; no disasm here — do not retry):
//   * m-init-0 + C-init fold of -m into QK^T MFMA      (R4 6.0, R5 1.55)
//   * l via ones-column MFMA accumulation              (R7 6.52)
//   * single-barrier V-dbuf merged with this softmax   (R10 0.203)
//   * __launch_bounds__ min-waves hint                 (R2 spill)
// Also: 16-row warps regressed (R9); OccupancyPercent reads ~0.5x theoretical.
__global__ __launch_bounds__(256) void k_attn(const __hip_bfloat16* __restrict__ qkv,
                                              __hip_bfloat16* __restrict__ nv) {
  __shared__ char lds[40960];
  const int t = threadIdx.x, l = t & 63, w = t >> 6;
  char* Ps = lds + 24576 + w * 4096;
  const int bid = blockIdx.x;
  const int wgid = (bid & 7) * 128 + (bid >> 3);   // XCD-chunked, bijective
  const int qi = wgid & 15;
  const int h  = (wgid >> 4) & 15;
  const int b  = wgid >> 8;
  const int q0 = qi * 128 + w * 32;
  const size_t seq0 = (size_t)b * 2048;
  const float LOG2E = 1.4426950408889634f;

  // Q fragments (A-operand), pre-scaled by log2(e)
  bf16x8 qf[2][2];
  #pragma unroll
  for (int mi = 0; mi < 2; ++mi)
    #pragma unroll
    for (int ks = 0; ks < 2; ++ks) {
      int row = q0 + mi * 16 + (l & 15);
      int col = ks * 32 + 8 * (l >> 4);
      bf16x8 raw = *(const bf16x8*)(qkv + (seq0 + row) * 3072 + h * 192 + col);
      #pragma unroll
      for (int j = 0; j < 8; ++j) {
        unsigned int u = ((unsigned int)(unsigned short)raw[j]) << 16;
        float f = __builtin_bit_cast(float, u) * LOG2E;
        qf[mi][ks][j] = (short)f2bf(f);
      }
    }

  // K: global_load_lds, dest linear, source pre-XOR-swizzled. Double-buffered.
  auto k_issue = [&](int kv0, char* Kd) {
    #pragma unroll
    for (int i = 0; i < 2; ++i) {
      int row = i * 32 + w * 8 + (l >> 3);
      int cl = (l & 7) ^ (l >> 3);
      const char* src = (const char*)(qkv + (seq0 + kv0 + row) * 3072 + h * 192 + 64 + cl * 8);
      __builtin_amdgcn_global_load_lds(
          (const __attribute__((address_space(1))) uint32_t*)src,
          (__attribute__((address_space(3))) uint32_t*)(Kd + w * 1024 + i * 4096),
          16, 0, 0);
    }
  };
  // V: reg-stage + transposed scatter at permuted position p = 4*(kv&15)+(kv>>4).
  // Single buffer: write happens between the two end-of-iteration barriers.
  const int vkv = t & 63, vdg = t >> 6;
  const int vp = 4 * (vkv & 15) + (vkv >> 4);
  const int vwithin = (2 * vp) & 15;
  const int vchunk = vp >> 3;
  union { uint4 q[2]; unsigned short s[16]; } vreg;
  auto v_issue = [&](int kv0) {
    const __hip_bfloat16* src = qkv + (seq0 + kv0 + vkv) * 3072 + h * 192 + 128 + vdg * 16;
    vreg.q[0] = *(const uint4*)(src);
    vreg.q[1] = *(const uint4*)(src + 8);
  };
  auto v_write = [&](char* Vd) {
    #pragma unroll
    for (int j = 0; j < 16; ++j) {
      int d = vdg * 16 + j;
      *(unsigned short*)(Vd + d * 128 + ((vchunk ^ (d & 7)) << 4) + vwithin) = vreg.s[j];
    }
  };

  f32x4 O[2][4] = {};
  float m_run[2][4], lp[2][4];   // lp = per-lane partial of l (deferred reduce)
  #pragma unroll
  for (int mi = 0; mi < 2; ++mi)
    #pragma unroll
    for (int r = 0; r < 4; ++r) { m_run[mi][r] = -1e30f; lp[mi][r] = 0.0f; }

  k_issue(0, lds);
  v_issue(0);
  v_write(lds + 16384);
  __syncthreads();

  for (int tIdx = 0; tIdx < 32; ++tIdx) {
    const int cur = tIdx & 1, nxt = cur ^ 1;
    const char* Kc = lds + cur * 8192;
    const char* Vc = lds + 16384;
    if (tIdx < 31) {
      k_issue((tIdx + 1) * 64, lds + nxt * 8192);
      v_issue((tIdx + 1) * 64);
    }

    // ---- S = Q K^T ----
    f32x4 S[2][4] = {};
    __builtin_amdgcn_s_setprio(1);
    #pragma unroll
    for (int ni = 0; ni < 4; ++ni) {
      int kvr = ni * 16 + (l & 15);
      #pragma unroll
      for (int ks = 0; ks < 2; ++ks) {
        bf16x8 kf = *(const bf16x8*)(Kc + kvr * 128 + (((ks * 4 + (l >> 4)) ^ (kvr & 7)) << 4));
        #pragma unroll
        for (int mi = 0; mi < 2; ++mi)
          S[mi][ni] = __builtin_amdgcn_mfma_f32_16x16x32_bf16(qf[mi][ks], kf, S[mi][ni], 0, 0, 0);
      }
    }
    __builtin_amdgcn_s_setprio(0);

    // ---- online softmax (exp2 domain) + packed P write ----
    // tm holds the LANE-LOCAL 4-column partial; check equivalent to the
    // row-max check under __all (m_run uniform per 16-lane row group).
    float tm[2][4];
    bool ok = true;
    #pragma unroll
    for (int mi = 0; mi < 2; ++mi)
      #pragma unroll
      for (int r = 0; r < 4; ++r) {
        float a = fmaxf(fmaxf(S[mi][0][r], S[mi][1][r]), fmaxf(S[mi][2][r], S[mi][3][r]));
        tm[mi][r] = a;
        ok = ok && (a <= m_run[mi][r] + 11.0f);
      }
    const int c = l & 15;
    if (__all(ok)) {
      // defer: m unchanged, no O rescale; lp accumulates lane-local partial
      #pragma unroll
      for (int mi = 0; mi < 2; ++mi)
        #pragma unroll
        for (int r = 0; r < 4; ++r) {
          float mn = m_run[mi][r];
          float p0 = __builtin_amdgcn_exp2f(S[mi][0][r] - mn);
          float p1 = __builtin_amdgcn_exp2f(S[mi][1][r] - mn);
          float p2 = __builtin_amdgcn_exp2f(S[mi][2][r] - mn);
          float p3 = __builtin_amdgcn_exp2f(S[mi][3][r] - mn);
          lp[mi][r] += (p0 + p1) + (p2 + p3);
          uint32_t d0, d1;
          asm("v_cvt_pk_bf16_f32 %0, %1, %2" : "=v"(d0) : "v"(p0), "v"(p1));
          asm("v_cvt_pk_bf16_f32 %0, %1, %2" : "=v"(d1) : "v"(p2), "v"(p3));
          uint2 pk; pk.x = d0; pk.y = d1;
          int q = mi * 16 + (l >> 4) * 4 + r;
          *(uint2*)(Ps + q * 128 + ((((c >> 1) ^ (q & 7))) << 4) + ((c & 1) << 3)) = pk;
        }
    } else {
      #pragma unroll
      for (int mi = 0; mi < 2; ++mi)
        #pragma unroll
        for (int r = 0; r < 4; ++r) {
          float mo = m_run[mi][r];
          float mn = fmaxf(mo, rowmax16(tm[mi][r]));   // full row max (slow path only)
          float sc = __builtin_amdgcn_exp2f(mo - mn);
          m_run[mi][r] = mn;
          float p0 = __builtin_amdgcn_exp2f(S[mi][0][r] - mn);
          float p1 = __builtin_amdgcn_exp2f(S[mi][1][r] - mn);
          float p2 = __builtin_amdgcn_exp2f(S[mi][2][r] - mn);
          float p3 = __builtin_amdgcn_exp2f(S[mi][3][r] - mn);
          lp[mi][r] = lp[mi][r] * sc + (p0 + p1) + (p2 + p3);
          O[mi][0][r] *= sc; O[mi][1][r] *= sc; O[mi][2][r] *= sc; O[mi][3][r] *= sc;
          uint32_t d0, d1;
          asm("v_cvt_pk_bf16_f32 %0, %1, %2" : "=v"(d0) : "v"(p0), "v"(p1));
          asm("v_cvt_pk_bf16_f32 %0, %1, %2" : "=v"(d1) : "v"(p2), "v"(p3));
          uint2 pk; pk.x = d0; pk.y = d1;
          int q = mi * 16 + (l >> 4) * 4 + r;
          *(uint2*)(Ps + q * 128 + ((((c >> 1) ^ (q & 7))) << 4) + ((c & 1) << 3)) = pk;
        }
    }

    // ---- O += P V  (positions are permuted identically on P and V) ----
    bf16x8 pa[2][2];
    #pragma unroll
    for (int mi = 0; mi < 2; ++mi) {
      int q = mi * 16 + (l & 15);
      #pragma unroll
      for (int ks = 0; ks < 2; ++ks)
        pa[mi][ks] = *(const bf16x8*)(Ps + q * 128 + (((ks * 4 + (l >> 4)) ^ (q & 7)) << 4));
    }
    __builtin_amdgcn_s_setprio(1);
    #pragma unroll
    for (int ni = 0; ni < 4; ++ni) {
      int dv = ni * 16 + (l & 15);
      #pragma unroll
      for (int ks = 0; ks < 2; ++ks) {
        bf16x8 vf = *(const bf16x8*)(Vc + dv * 128 + (((ks * 4 + (l >> 4)) ^ (dv & 7)) << 4));
        #pragma unroll
        for (int mi = 0; mi < 2; ++mi)
          O[mi][ni] = __builtin_amdgcn_mfma_f32_16x16x32_bf16(pa[mi][ks], vf, O[mi][ni], 0, 0, 0);
      }
    }
    __builtin_amdgcn_s_setprio(0);

    __syncthreads();                    // all waves done reading V(t) (drains prefetch too)
    if (tIdx < 31) v_write(lds + 16384);
    __syncthreads();                    // V(t+1) visible to all waves
  }

  #pragma unroll
  for (int mi = 0; mi < 2; ++mi) {
    #pragma unroll
    for (int r = 0; r < 4; ++r) {
      float inv = 1.0f / rowsum16(lp[mi][r]);   // single deferred 16-lane reduce
      int row = q0 + mi * 16 + (l >> 4) * 4 + r;
      #pragma unroll
      for (int ni = 0; ni < 4; ++ni) {
        int col = h * 64 + ni * 16 + (l & 15);
        *(unsigned short*)((char*)nv + (((seq0 + row) * 1024 + col)) * 2) =
            f2bf(O[mi][ni][r] * inv);
      }
    }
  }
}

// =================== LayerNorm (in-place on d_out, row = 1024 fp32) ===================
__global__ __launch_bounds__(256) void k_ln(float* __restrict__ io) {
  int row = blockIdx.x, t = threadIdx.x;
  float* p = io + (size_t)row * 1024;
  float4 v = *(const float4*)(p + t * 4);
  float s = v.x + v.y + v.z + v.w;
  float q = v.x * v.x + v.y * v.y + v.z * v.z + v.w * v.w;
  #pragma unroll
  for (int off = 32; off > 0; off >>= 1) { s += __shfl_xor(s, off); q += __shfl_xor(q, off); }
  __shared__ float red[8];
  if ((t & 63) == 0) { red[t >> 6] = s; red[4 + (t >> 6)] = q; }
  __syncthreads();
  s = red[0] + red[1] + red[2] + red[3];
  q = red[4] + red[5] + red[6] + red[7];
  float mu = s * (1.0f / 1024.0f);
  float var = q * (1.0f / 1024.0f) - mu * mu;
  float rs = rsqrtf(var + 1e-5f);
  float4 o;
  o.x = (v.x - mu) * rs; o.y = (v.y - mu) * rs; o.z = (v.z - mu) * rs; o.w = (v.w - mu) * rs;
  *(float4*)(p + t * 4) = o;
}

// =================== launch ===================
extern "C" void kernel_launch(void* const* d_in, const int* in_sizes, int n_in,
                              void* d_out, int out_size, void* d_ws, size_t ws_size,
                              hipStream_t stream) {
  const float* x    = (const float*)d_in[0];   // [4,2048,1024]
  const float* Wfc  = (const float*)d_in[1];   // [1024,3072]
  const float* bfc  = (const float*)d_in[2];   // [3072]
  const float* Wout = (const float*)d_in[3];   // [1024,1024]
  const float* bout = (const float*)d_in[4];   // [1024]
  float* out = (float*)d_out;                  // [4,2048,1024] fp32

  char* ws = (char*)d_ws;
  __hip_bfloat16* xb   = (__hip_bfloat16*)(ws);                 // 16,777,216 B
  __hip_bfloat16* wfct = (__hip_bfloat16*)(ws + 16777216);      //  6,291,456 B [3072][1024]
  __hip_bfloat16* wot  = (__hip_bfloat16*)(ws + 23068672);      //  2,097,152 B [1024][1024]
  __hip_bfloat16* qkvb = (__hip_bfloat16*)(ws + 25165824);      // 50,331,648 B [8192][3072]
  __hip_bfloat16* nvb  = (__hip_bfloat16*)(ws + 75497472);      // 16,777,216 B [8192][1024]

  k_cvt_bf16<<<4096, 256, 0, stream>>>(x, xb);
  k_transpose_bf16<<<dim3(96, 32), 256, 0, stream>>>(Wfc, wfct, 1024, 3072);
  k_transpose_bf16<<<dim3(32, 32), 256, 0, stream>>>(Wout, wot, 1024, 1024);
  k_gemm_fc<<<1536, 256, 0, stream>>>(xb, wfct, bfc, qkvb, 8192, 3072, 1024);
  k_attn<<<1024, 256, 0, stream>>>(qkvb, nvb);
  k_gemm_out<<<512, 256, 0, stream>>>(nvb, wot, bout, x, out, 8192, 1024, 1024);
  k_ln<<<8192, 256, 0, stream>>>(out);
}